// Round 1
// baseline (376.985 us; speedup 1.0000x reference)
//
#include <hip/hip_runtime.h>
#include <hip/hip_bf16.h>
#include <math.h>

#define HID 128
#define ODIM 64

// ---------------------------------------------------------------------------
// Detect whether edge_index buffer is int64 (JAX x64 on) or int32.
// If int64 with values < 2^31, every odd 32-bit word (high half) is 0.
// For int32 random indices in [0,50000), 64 consecutive odd words all being
// zero has probability ~(2e-5)^64 ~= 0.
// ---------------------------------------------------------------------------
__global__ void detect_idx_kernel(const unsigned int* __restrict__ ei_words,
                                  int* __restrict__ flag) {
  int t = threadIdx.x;  // 64 threads
  unsigned int v = ei_words[2 * t + 1];
  unsigned long long b = __ballot(v == 0u);
  if (t == 0) *flag = (b == 0xFFFFFFFFFFFFFFFFull) ? 1 : 0;
}

__device__ inline int edge_val(const void* ei, int is64, long long idx) {
  if (is64) return (int)((const long long*)ei)[idx];
  return ((const int*)ei)[idx];
}

// ---------------------------------------------------------------------------
// In-degree count (targets = col = edge_index[1]).
// ---------------------------------------------------------------------------
__global__ void count_kernel(const void* __restrict__ ei, int E,
                             const int* __restrict__ flag,
                             unsigned int* __restrict__ count) {
  int is64 = *flag;
  for (int e = blockIdx.x * blockDim.x + threadIdx.x; e < E;
       e += gridDim.x * blockDim.x) {
    int col = edge_val(ei, is64, (long long)E + e);
    atomicAdd(&count[col], 1u);
  }
}

// ---------------------------------------------------------------------------
// Single-block exclusive scan of counts -> CSR offsets, plus dinv = rsqrt(deg)
// with deg = 1 (self-loop) + in-count.
// ---------------------------------------------------------------------------
__global__ __launch_bounds__(1024) void scan_kernel(
    const unsigned int* __restrict__ count, unsigned int* __restrict__ offsets,
    float* __restrict__ dinv, int n) {
  __shared__ unsigned int sums[1024];
  int tid = threadIdx.x;
  int chunk = (n + 1023) >> 10;
  int s = tid * chunk;
  int e = min(s + chunk, n);
  unsigned int local = 0;
  for (int i = s; i < e; ++i) local += count[i];
  sums[tid] = local;
  __syncthreads();
  // Hillis-Steele inclusive scan over 1024 partials
  for (int d = 1; d < 1024; d <<= 1) {
    unsigned int v = (tid >= d) ? sums[tid - d] : 0u;
    __syncthreads();
    sums[tid] += v;
    __syncthreads();
  }
  unsigned int run = sums[tid] - local;  // exclusive base for this chunk
  for (int i = s; i < e; ++i) {
    offsets[i] = run;
    unsigned int c = count[i];
    run += c;
    dinv[i] = rsqrtf((float)(1u + c));
  }
  if (tid == 0) offsets[n] = sums[1023];
}

// ---------------------------------------------------------------------------
// Fill CSR buckets: for each edge, ebuf[offsets[col] + pos] = row.
// ---------------------------------------------------------------------------
__global__ void fill_kernel(const void* __restrict__ ei, int E,
                            const int* __restrict__ flag,
                            const unsigned int* __restrict__ offsets,
                            unsigned int* __restrict__ cursor,
                            int* __restrict__ ebuf) {
  int is64 = *flag;
  for (int e = blockIdx.x * blockDim.x + threadIdx.x; e < E;
       e += gridDim.x * blockDim.x) {
    int row = edge_val(ei, is64, e);
    int col = edge_val(ei, is64, (long long)E + e);
    unsigned int pos = atomicAdd(&cursor[col], 1u);
    ebuf[offsets[col] + pos] = row;
  }
}

// ---------------------------------------------------------------------------
// GEMM [N,128] @ [128,128] (+bias, optional relu). W in LDS (64KB), 32 rows of
// A staged per iter. Each wave: 8 rows x 2 cols (c, c+64) in registers.
// VALU-bound by design: per 4 k-steps, 8 broadcast b128 + 8 b32 LDS reads vs
// 64 FMA wave-instructions.
// ---------------------------------------------------------------------------
__global__ __launch_bounds__(256, 2) void gemm128_kernel(
    const float* __restrict__ A, const float* __restrict__ W,
    const float* __restrict__ bias, float* __restrict__ out, int nrows,
    int do_relu) {
  __shared__ float Wl[HID * HID];
  __shared__ float Zl[32][HID];
  for (int i = threadIdx.x; i < HID * HID; i += 256) Wl[i] = W[i];
  int wave = threadIdx.x >> 6, lane = threadIdx.x & 63;
  int c0 = lane, c1 = lane + 64;
  float b0 = bias ? bias[c0] : 0.f;
  float b1v = bias ? bias[c1] : 0.f;
  __syncthreads();
  for (int base = blockIdx.x * 32; base < nrows; base += gridDim.x * 32) {
    int nr = min(32, nrows - base);
    const float4* src = (const float4*)(A + (size_t)base * HID);
    for (int i = threadIdx.x; i < nr * 32; i += 256)
      ((float4*)&Zl[0][0])[i] = src[i];
    __syncthreads();
    float acc[8][2];
#pragma unroll
    for (int r = 0; r < 8; ++r) {
      acc[r][0] = 0.f;
      acc[r][1] = 0.f;
    }
    int r0 = wave * 8;
#pragma unroll 2
    for (int k4 = 0; k4 < 32; ++k4) {
      float4 zq[8];
#pragma unroll
      for (int r = 0; r < 8; ++r) zq[r] = *(const float4*)&Zl[r0 + r][k4 * 4];
#pragma unroll
      for (int kk = 0; kk < 4; ++kk) {
        float w0 = Wl[(k4 * 4 + kk) * HID + c0];
        float w1 = Wl[(k4 * 4 + kk) * HID + c1];
#pragma unroll
        for (int r = 0; r < 8; ++r) {
          float zv = ((const float*)&zq[r])[kk];
          acc[r][0] = fmaf(zv, w0, acc[r][0]);
          acc[r][1] = fmaf(zv, w1, acc[r][1]);
        }
      }
    }
#pragma unroll
    for (int r = 0; r < 8; ++r) {
      int row = r0 + r;
      if (row < nr) {
        float v0 = acc[r][0] + b0;
        float v1 = acc[r][1] + b1v;
        if (do_relu) {
          v0 = fmaxf(v0, 0.f);
          v1 = fmaxf(v1, 0.f);
        }
        size_t o = (size_t)(base + row) * HID;
        out[o + c0] = v0;
        out[o + c1] = v1;
      }
    }
    __syncthreads();
  }
}

// ---------------------------------------------------------------------------
// Final GEMM [N,128] @ [128,64] + b2, sigmoid on column 0.
// ---------------------------------------------------------------------------
__global__ __launch_bounds__(256) void gemm_out_kernel(
    const float* __restrict__ A, const float* __restrict__ W,
    const float* __restrict__ bias, float* __restrict__ out, int nrows) {
  __shared__ float Wl[HID * ODIM];
  __shared__ float Zl[32][HID];
  for (int i = threadIdx.x; i < HID * ODIM; i += 256) Wl[i] = W[i];
  int wave = threadIdx.x >> 6, lane = threadIdx.x & 63;
  float bc = bias[lane];
  __syncthreads();
  for (int base = blockIdx.x * 32; base < nrows; base += gridDim.x * 32) {
    int nr = min(32, nrows - base);
    const float4* src = (const float4*)(A + (size_t)base * HID);
    for (int i = threadIdx.x; i < nr * 32; i += 256)
      ((float4*)&Zl[0][0])[i] = src[i];
    __syncthreads();
    float acc[8];
#pragma unroll
    for (int r = 0; r < 8; ++r) acc[r] = 0.f;
    int r0 = wave * 8;
#pragma unroll 2
    for (int k4 = 0; k4 < 32; ++k4) {
      float4 zq[8];
#pragma unroll
      for (int r = 0; r < 8; ++r) zq[r] = *(const float4*)&Zl[r0 + r][k4 * 4];
#pragma unroll
      for (int kk = 0; kk < 4; ++kk) {
        float w = Wl[(k4 * 4 + kk) * ODIM + lane];
#pragma unroll
        for (int r = 0; r < 8; ++r) {
          float zv = ((const float*)&zq[r])[kk];
          acc[r] = fmaf(zv, w, acc[r]);
        }
      }
    }
#pragma unroll
    for (int r = 0; r < 8; ++r) {
      int row = r0 + r;
      if (row < nr) {
        float v = acc[r] + bc;
        if (lane == 0) v = 1.f / (1.f + __expf(-v));
        out[(size_t)(base + row) * ODIM + lane] = v;
      }
    }
    __syncthreads();
  }
}

// ---------------------------------------------------------------------------
// Per-node aggregation: one wave per node, float2 per lane (128 channels).
// acc = xw[i]*dinv[i]^2 (self loop) + sum_{edges j->i} xw[j]*dinv[j]*dinv[i].
// Then h2 = relu(acc + bg). No atomics.
// ---------------------------------------------------------------------------
__global__ __launch_bounds__(256) void agg_kernel(
    const float* __restrict__ xw, const float* __restrict__ dinv,
    const unsigned int* __restrict__ offsets, const int* __restrict__ ebuf,
    const float* __restrict__ bg, float* __restrict__ h2, int n) {
  int lane = threadIdx.x & 63;
  int wid = (blockIdx.x * blockDim.x + threadIdx.x) >> 6;
  int nw = (gridDim.x * blockDim.x) >> 6;
  const float2* xw2 = (const float2*)xw;
  float2 bgv = ((const float2*)bg)[lane];
  for (int i = wid; i < n; i += nw) {
    float di = dinv[i];
    float2 acc = xw2[(size_t)i * 64 + lane];
    float sw = di * di;
    acc.x *= sw;
    acc.y *= sw;
    unsigned int s = offsets[i];
    unsigned int e = offsets[i + 1];
    for (unsigned int t = s; t < e; ++t) {
      int r = ebuf[t];
      r = __builtin_amdgcn_readfirstlane(r);  // wave-uniform -> SGPR
      float nrm = dinv[r] * di;
      float2 v = xw2[(size_t)r * 64 + lane];
      acc.x = fmaf(v.x, nrm, acc.x);
      acc.y = fmaf(v.y, nrm, acc.y);
    }
    float2 o;
    o.x = fmaxf(acc.x + bgv.x, 0.f);
    o.y = fmaxf(acc.y + bgv.y, 0.f);
    ((float2*)h2)[(size_t)i * 64 + lane] = o;
  }
}

// ---------------------------------------------------------------------------
static inline size_t align16(size_t x) { return (x + 15) & ~(size_t)15; }

extern "C" void kernel_launch(void* const* d_in, const int* in_sizes, int n_in,
                              void* d_out, int out_size, void* d_ws,
                              size_t ws_size, hipStream_t stream) {
  const float* z = (const float*)d_in[0];
  const float* W1 = (const float*)d_in[1];
  const float* b1 = (const float*)d_in[2];
  const float* Wg = (const float*)d_in[3];
  const float* bg = (const float*)d_in[4];
  const float* W2 = (const float*)d_in[5];
  const float* b2 = (const float*)d_in[6];
  const void* ei = d_in[7];

  int N = in_sizes[0] / HID;
  int E = in_sizes[7] / 2;

  char* ws = (char*)d_ws;
  size_t szH = align16((size_t)N * HID * sizeof(float));
  float* h = (float*)ws;            // [N,128]  (later reused for h2)
  float* xw = (float*)(ws + szH);   // [N,128]
  char* p = ws + 2 * szH;
  float* dinv = (float*)p;          p += align16((size_t)N * 4);
  unsigned int* offsets = (unsigned int*)p;  p += align16((size_t)(N + 1) * 4);
  unsigned int* count = (unsigned int*)p;    p += align16((size_t)N * 4);
  unsigned int* cursor = (unsigned int*)p;   p += align16((size_t)N * 4);
  int* ebuf = (int*)p;              p += align16((size_t)E * 4);
  int* flag = (int*)p;

  // zero count + cursor (contiguous region) 
  hipMemsetAsync(count, 0, (size_t)((char*)ebuf - (char*)count), stream);

  detect_idx_kernel<<<1, 64, 0, stream>>>((const unsigned int*)ei, flag);

  // h = relu(z @ W1 + b1)
  gemm128_kernel<<<512, 256, 0, stream>>>(z, W1, b1, h, N, 1);

  // CSR build
  count_kernel<<<1024, 256, 0, stream>>>(ei, E, flag, count);
  scan_kernel<<<1, 1024, 0, stream>>>(count, offsets, dinv, N);
  fill_kernel<<<1024, 256, 0, stream>>>(ei, E, flag, offsets, cursor, ebuf);

  // xw = h @ Wg
  gemm128_kernel<<<512, 256, 0, stream>>>(h, Wg, nullptr, xw, N, 0);

  // h2 = relu(agg + bg)   (overwrites h)
  agg_kernel<<<2048, 256, 0, stream>>>(xw, dinv, offsets, ebuf, bg, h, N);

  // out = h2 @ W2 + b2, sigmoid col 0
  gemm_out_kernel<<<768, 256, 0, stream>>>(h, W2, b2, (float*)d_out, N);
}

// Round 2
// 277.930 us; speedup vs baseline: 1.3564x; 1.3564x over previous
//
#include <hip/hip_runtime.h>
#include <hip/hip_bf16.h>
#include <math.h>

#define HID 128
#define ODIM 64

// ---------------------------------------------------------------------------
// Detect whether edge_index buffer is int64 (JAX x64 on) or int32.
// If int64 with values < 2^31, every odd 32-bit word (high half) is 0.
// ---------------------------------------------------------------------------
__global__ void detect_idx_kernel(const unsigned int* __restrict__ ei_words,
                                  int* __restrict__ flag) {
  int t = threadIdx.x;  // 64 threads
  unsigned int v = ei_words[2 * t + 1];
  unsigned long long b = __ballot(v == 0u);
  if (t == 0) *flag = (b == 0xFFFFFFFFFFFFFFFFull) ? 1 : 0;
}

__device__ inline int edge_val(const void* ei, int is64, long long idx) {
  if (is64) return (int)((const long long*)ei)[idx];
  return ((const int*)ei)[idx];
}

// ---------------------------------------------------------------------------
// In-degree count (targets = col = edge_index[1]).
// ---------------------------------------------------------------------------
__global__ void count_kernel(const void* __restrict__ ei, int E,
                             const int* __restrict__ flag,
                             unsigned int* __restrict__ count) {
  int is64 = *flag;
  for (int e = blockIdx.x * blockDim.x + threadIdx.x; e < E;
       e += gridDim.x * blockDim.x) {
    int col = edge_val(ei, is64, (long long)E + e);
    atomicAdd(&count[col], 1u);
  }
}

// ---------------------------------------------------------------------------
// 3-pass device-wide exclusive scan of count[0..n) -> offsets, plus
// dinv = rsqrt(1 + count). TILE = 1024 elements per 256-thread block.
// ---------------------------------------------------------------------------
__global__ __launch_bounds__(256) void scan_part_kernel(
    const unsigned int* __restrict__ count, unsigned int* __restrict__ bsums,
    int n) {
  int base = blockIdx.x * 1024 + threadIdx.x * 4;
  unsigned int s = 0;
  if (base + 4 <= n) {
    uint4 c = *(const uint4*)&count[base];
    s = c.x + c.y + c.z + c.w;
  } else {
#pragma unroll
    for (int j = 0; j < 4; ++j) s += (base + j < n) ? count[base + j] : 0u;
  }
#pragma unroll
  for (int d = 32; d >= 1; d >>= 1) s += __shfl_down(s, d, 64);
  __shared__ unsigned int red[4];
  int wave = threadIdx.x >> 6, lane = threadIdx.x & 63;
  if (lane == 0) red[wave] = s;
  __syncthreads();
  if (threadIdx.x == 0)
    bsums[blockIdx.x] = red[0] + red[1] + red[2] + red[3];
}

__global__ void scan_top_kernel(const unsigned int* __restrict__ bsums,
                                unsigned int* __restrict__ bbase, int nb) {
  int t = threadIdx.x;  // 64 threads, single wave
  unsigned int run = 0;
  for (int s0 = 0; s0 < nb; s0 += 64) {
    unsigned int v = (s0 + t < nb) ? bsums[s0 + t] : 0u;
    unsigned int incl = v;
#pragma unroll
    for (int d = 1; d < 64; d <<= 1) {
      unsigned int u = __shfl_up(incl, d, 64);
      if (t >= d) incl += u;
    }
    if (s0 + t < nb) bbase[s0 + t] = run + incl - v;
    run += __shfl(incl, 63, 64);
  }
}

__global__ __launch_bounds__(256) void scan_final_kernel(
    const unsigned int* __restrict__ count,
    const unsigned int* __restrict__ bbase, unsigned int* __restrict__ offsets,
    float* __restrict__ dinv, int n, int E) {
  int base = blockIdx.x * 1024 + threadIdx.x * 4;
  unsigned int c[4];
  if (base + 4 <= n) {
    uint4 cv = *(const uint4*)&count[base];
    c[0] = cv.x; c[1] = cv.y; c[2] = cv.z; c[3] = cv.w;
  } else {
#pragma unroll
    for (int j = 0; j < 4; ++j) c[j] = (base + j < n) ? count[base + j] : 0u;
  }
  unsigned int tsum = c[0] + c[1] + c[2] + c[3];
  unsigned int incl = tsum;
#pragma unroll
  for (int d = 1; d < 64; d <<= 1) {
    unsigned int u = __shfl_up(incl, d, 64);
    if ((threadIdx.x & 63) >= d) incl += u;
  }
  __shared__ unsigned int wsum[4];
  int wave = threadIdx.x >> 6;
  if ((threadIdx.x & 63) == 63) wsum[wave] = incl;
  __syncthreads();
  unsigned int ex = bbase[blockIdx.x] + incl - tsum;
  for (int w = 0; w < wave; ++w) ex += wsum[w];
  unsigned int o[4];
  float dv[4];
#pragma unroll
  for (int j = 0; j < 4; ++j) {
    o[j] = ex;
    ex += c[j];
    dv[j] = rsqrtf((float)(1u + c[j]));
  }
  if (base + 4 <= n) {
    *(uint4*)&offsets[base] = make_uint4(o[0], o[1], o[2], o[3]);
    *(float4*)&dinv[base] = make_float4(dv[0], dv[1], dv[2], dv[3]);
  } else {
#pragma unroll
    for (int j = 0; j < 4; ++j)
      if (base + j < n) {
        offsets[base + j] = o[j];
        dinv[base + j] = dv[j];
      }
  }
  // Total over all counts is exactly E (each edge has one target).
  if (blockIdx.x == 0 && threadIdx.x == 0) offsets[n] = (unsigned int)E;
}

// ---------------------------------------------------------------------------
// Fill CSR buckets: for each edge, ebuf[offsets[col] + pos] = row.
// ---------------------------------------------------------------------------
__global__ void fill_kernel(const void* __restrict__ ei, int E,
                            const int* __restrict__ flag,
                            const unsigned int* __restrict__ offsets,
                            unsigned int* __restrict__ cursor,
                            int* __restrict__ ebuf) {
  int is64 = *flag;
  for (int e = blockIdx.x * blockDim.x + threadIdx.x; e < E;
       e += gridDim.x * blockDim.x) {
    int row = edge_val(ei, is64, e);
    int col = edge_val(ei, is64, (long long)E + e);
    unsigned int pos = atomicAdd(&cursor[col], 1u);
    ebuf[offsets[col] + pos] = row;
  }
}

// ---------------------------------------------------------------------------
// GEMM [N,128] @ [128,128] (+bias, optional relu). W in LDS (64KB), 32 rows of
// A staged per iter. Each wave: 8 rows x 2 cols (c, c+64) in registers.
// ---------------------------------------------------------------------------
__global__ __launch_bounds__(256, 2) void gemm128_kernel(
    const float* __restrict__ A, const float* __restrict__ W,
    const float* __restrict__ bias, float* __restrict__ out, int nrows,
    int do_relu) {
  __shared__ float Wl[HID * HID];
  __shared__ float Zl[32][HID];
  for (int i = threadIdx.x; i < HID * HID; i += 256) Wl[i] = W[i];
  int wave = threadIdx.x >> 6, lane = threadIdx.x & 63;
  int c0 = lane, c1 = lane + 64;
  float b0 = bias ? bias[c0] : 0.f;
  float b1v = bias ? bias[c1] : 0.f;
  __syncthreads();
  for (int base = blockIdx.x * 32; base < nrows; base += gridDim.x * 32) {
    int nr = min(32, nrows - base);
    const float4* src = (const float4*)(A + (size_t)base * HID);
    for (int i = threadIdx.x; i < nr * 32; i += 256)
      ((float4*)&Zl[0][0])[i] = src[i];
    __syncthreads();
    float acc[8][2];
#pragma unroll
    for (int r = 0; r < 8; ++r) {
      acc[r][0] = 0.f;
      acc[r][1] = 0.f;
    }
    int r0 = wave * 8;
#pragma unroll 2
    for (int k4 = 0; k4 < 32; ++k4) {
      float4 zq[8];
#pragma unroll
      for (int r = 0; r < 8; ++r) zq[r] = *(const float4*)&Zl[r0 + r][k4 * 4];
#pragma unroll
      for (int kk = 0; kk < 4; ++kk) {
        float w0 = Wl[(k4 * 4 + kk) * HID + c0];
        float w1 = Wl[(k4 * 4 + kk) * HID + c1];
#pragma unroll
        for (int r = 0; r < 8; ++r) {
          float zv = ((const float*)&zq[r])[kk];
          acc[r][0] = fmaf(zv, w0, acc[r][0]);
          acc[r][1] = fmaf(zv, w1, acc[r][1]);
        }
      }
    }
#pragma unroll
    for (int r = 0; r < 8; ++r) {
      int row = r0 + r;
      if (row < nr) {
        float v0 = acc[r][0] + b0;
        float v1 = acc[r][1] + b1v;
        if (do_relu) {
          v0 = fmaxf(v0, 0.f);
          v1 = fmaxf(v1, 0.f);
        }
        size_t o = (size_t)(base + row) * HID;
        out[o + c0] = v0;
        out[o + c1] = v1;
      }
    }
    __syncthreads();
  }
}

// ---------------------------------------------------------------------------
// Final GEMM [N,128] @ [128,64] + b2, sigmoid on column 0.
// ---------------------------------------------------------------------------
__global__ __launch_bounds__(256) void gemm_out_kernel(
    const float* __restrict__ A, const float* __restrict__ W,
    const float* __restrict__ bias, float* __restrict__ out, int nrows) {
  __shared__ float Wl[HID * ODIM];
  __shared__ float Zl[32][HID];
  for (int i = threadIdx.x; i < HID * ODIM; i += 256) Wl[i] = W[i];
  int wave = threadIdx.x >> 6, lane = threadIdx.x & 63;
  float bc = bias[lane];
  __syncthreads();
  for (int base = blockIdx.x * 32; base < nrows; base += gridDim.x * 32) {
    int nr = min(32, nrows - base);
    const float4* src = (const float4*)(A + (size_t)base * HID);
    for (int i = threadIdx.x; i < nr * 32; i += 256)
      ((float4*)&Zl[0][0])[i] = src[i];
    __syncthreads();
    float acc[8];
#pragma unroll
    for (int r = 0; r < 8; ++r) acc[r] = 0.f;
    int r0 = wave * 8;
#pragma unroll 2
    for (int k4 = 0; k4 < 32; ++k4) {
      float4 zq[8];
#pragma unroll
      for (int r = 0; r < 8; ++r) zq[r] = *(const float4*)&Zl[r0 + r][k4 * 4];
#pragma unroll
      for (int kk = 0; kk < 4; ++kk) {
        float w = Wl[(k4 * 4 + kk) * ODIM + lane];
#pragma unroll
        for (int r = 0; r < 8; ++r) {
          float zv = ((const float*)&zq[r])[kk];
          acc[r] = fmaf(zv, w, acc[r]);
        }
      }
    }
#pragma unroll
    for (int r = 0; r < 8; ++r) {
      int row = r0 + r;
      if (row < nr) {
        float v = acc[r] + bc;
        if (lane == 0) v = 1.f / (1.f + __expf(-v));
        out[(size_t)(base + row) * ODIM + lane] = v;
      }
    }
    __syncthreads();
  }
}

// ---------------------------------------------------------------------------
// Per-node aggregation: one wave per node, float2 per lane (128 channels).
// ---------------------------------------------------------------------------
__global__ __launch_bounds__(256) void agg_kernel(
    const float* __restrict__ xw, const float* __restrict__ dinv,
    const unsigned int* __restrict__ offsets, const int* __restrict__ ebuf,
    const float* __restrict__ bg, float* __restrict__ h2, int n) {
  int lane = threadIdx.x & 63;
  int wid = (blockIdx.x * blockDim.x + threadIdx.x) >> 6;
  int nw = (gridDim.x * blockDim.x) >> 6;
  const float2* xw2 = (const float2*)xw;
  float2 bgv = ((const float2*)bg)[lane];
  for (int i = wid; i < n; i += nw) {
    float di = dinv[i];
    float2 acc = xw2[(size_t)i * 64 + lane];
    float sw = di * di;
    acc.x *= sw;
    acc.y *= sw;
    unsigned int s = offsets[i];
    unsigned int e = offsets[i + 1];
    for (unsigned int t = s; t < e; ++t) {
      int r = ebuf[t];
      r = __builtin_amdgcn_readfirstlane(r);  // wave-uniform -> SGPR
      float nrm = dinv[r] * di;
      float2 v = xw2[(size_t)r * 64 + lane];
      acc.x = fmaf(v.x, nrm, acc.x);
      acc.y = fmaf(v.y, nrm, acc.y);
    }
    float2 o;
    o.x = fmaxf(acc.x + bgv.x, 0.f);
    o.y = fmaxf(acc.y + bgv.y, 0.f);
    ((float2*)h2)[(size_t)i * 64 + lane] = o;
  }
}

// ---------------------------------------------------------------------------
static inline size_t align16(size_t x) { return (x + 15) & ~(size_t)15; }

extern "C" void kernel_launch(void* const* d_in, const int* in_sizes, int n_in,
                              void* d_out, int out_size, void* d_ws,
                              size_t ws_size, hipStream_t stream) {
  const float* z = (const float*)d_in[0];
  const float* W1 = (const float*)d_in[1];
  const float* b1 = (const float*)d_in[2];
  const float* Wg = (const float*)d_in[3];
  const float* bg = (const float*)d_in[4];
  const float* W2 = (const float*)d_in[5];
  const float* b2 = (const float*)d_in[6];
  const void* ei = d_in[7];

  int N = in_sizes[0] / HID;
  int E = in_sizes[7] / 2;
  int NB = (N + 1023) / 1024;

  char* ws = (char*)d_ws;
  size_t szH = align16((size_t)N * HID * sizeof(float));
  float* h = (float*)ws;            // [N,128]  (later reused for h2)
  float* xw = (float*)(ws + szH);   // [N,128]
  char* p = ws + 2 * szH;
  float* dinv = (float*)p;          p += align16((size_t)N * 4);
  unsigned int* offsets = (unsigned int*)p;  p += align16((size_t)(N + 1) * 4);
  unsigned int* count = (unsigned int*)p;    p += align16((size_t)N * 4);
  unsigned int* cursor = (unsigned int*)p;   p += align16((size_t)N * 4);
  int* ebuf = (int*)p;              p += align16((size_t)E * 4);
  int* flag = (int*)p;              p += align16(4);
  unsigned int* bsums = (unsigned int*)p;    p += align16((size_t)NB * 4);
  unsigned int* bbase = (unsigned int*)p;

  // zero count + cursor (contiguous region)
  hipMemsetAsync(count, 0, (size_t)((char*)ebuf - (char*)count), stream);

  detect_idx_kernel<<<1, 64, 0, stream>>>((const unsigned int*)ei, flag);

  // h = relu(z @ W1 + b1)
  gemm128_kernel<<<512, 256, 0, stream>>>(z, W1, b1, h, N, 1);

  // CSR build: count -> 3-pass scan -> fill
  count_kernel<<<1024, 256, 0, stream>>>(ei, E, flag, count);
  scan_part_kernel<<<NB, 256, 0, stream>>>(count, bsums, N);
  scan_top_kernel<<<1, 64, 0, stream>>>(bsums, bbase, NB);
  scan_final_kernel<<<NB, 256, 0, stream>>>(count, bbase, offsets, dinv, N, E);
  fill_kernel<<<1024, 256, 0, stream>>>(ei, E, flag, offsets, cursor, ebuf);

  // xw = h @ Wg
  gemm128_kernel<<<512, 256, 0, stream>>>(h, Wg, nullptr, xw, N, 0);

  // h2 = relu(agg + bg)   (overwrites h)
  agg_kernel<<<2048, 256, 0, stream>>>(xw, dinv, offsets, ebuf, bg, h, N);

  // out = h2 @ W2 + b2, sigmoid col 0
  gemm_out_kernel<<<768, 256, 0, stream>>>(h, W2, b2, (float*)d_out, N);
}

// Round 3
// 234.796 us; speedup vs baseline: 1.6056x; 1.1837x over previous
//
#include <hip/hip_runtime.h>
#include <hip/hip_bf16.h>
#include <math.h>

#define HID 128
#define ODIM 64

// ---------------------------------------------------------------------------
// bf16 pack (round-to-nearest-even) : two floats -> one u32 (lo, hi)
// ---------------------------------------------------------------------------
__device__ inline unsigned pack_bf16(float a, float b) {
  unsigned ua = __float_as_uint(a), ub = __float_as_uint(b);
  ua += 0x7fffu + ((ua >> 16) & 1u);
  ub += 0x7fffu + ((ub >> 16) & 1u);
  return (ua >> 16) | (ub & 0xffff0000u);
}
__device__ inline float bf16_lo(unsigned u) { return __uint_as_float(u << 16); }
__device__ inline float bf16_hi(unsigned u) {
  return __uint_as_float(u & 0xffff0000u);
}

// ---------------------------------------------------------------------------
// Detect whether edge_index buffer is int64 (JAX x64 on) or int32.
// ---------------------------------------------------------------------------
__global__ void detect_idx_kernel(const unsigned int* __restrict__ ei_words,
                                  int* __restrict__ flag) {
  int t = threadIdx.x;  // 64 threads
  unsigned int v = ei_words[2 * t + 1];
  unsigned long long b = __ballot(v == 0u);
  if (t == 0) *flag = (b == 0xFFFFFFFFFFFFFFFFull) ? 1 : 0;
}

__device__ inline int edge_val(const void* ei, int is64, long long idx) {
  if (is64) return (int)((const long long*)ei)[idx];
  return ((const int*)ei)[idx];
}

// ---------------------------------------------------------------------------
// In-degree count (targets = col = edge_index[1]).
// ---------------------------------------------------------------------------
__global__ void count_kernel(const void* __restrict__ ei, int E,
                             const int* __restrict__ flag,
                             unsigned int* __restrict__ count) {
  int is64 = *flag;
  for (int e = blockIdx.x * blockDim.x + threadIdx.x; e < E;
       e += gridDim.x * blockDim.x) {
    int col = edge_val(ei, is64, (long long)E + e);
    atomicAdd(&count[col], 1u);
  }
}

// ---------------------------------------------------------------------------
// 3-pass device-wide exclusive scan of count -> offsets, plus dinv.
// ---------------------------------------------------------------------------
__global__ __launch_bounds__(256) void scan_part_kernel(
    const unsigned int* __restrict__ count, unsigned int* __restrict__ bsums,
    int n) {
  int base = blockIdx.x * 1024 + threadIdx.x * 4;
  unsigned int s = 0;
  if (base + 4 <= n) {
    uint4 c = *(const uint4*)&count[base];
    s = c.x + c.y + c.z + c.w;
  } else {
#pragma unroll
    for (int j = 0; j < 4; ++j) s += (base + j < n) ? count[base + j] : 0u;
  }
#pragma unroll
  for (int d = 32; d >= 1; d >>= 1) s += __shfl_down(s, d, 64);
  __shared__ unsigned int red[4];
  int wave = threadIdx.x >> 6, lane = threadIdx.x & 63;
  if (lane == 0) red[wave] = s;
  __syncthreads();
  if (threadIdx.x == 0) bsums[blockIdx.x] = red[0] + red[1] + red[2] + red[3];
}

__global__ void scan_top_kernel(const unsigned int* __restrict__ bsums,
                                unsigned int* __restrict__ bbase, int nb) {
  int t = threadIdx.x;  // 64 threads, single wave
  unsigned int run = 0;
  for (int s0 = 0; s0 < nb; s0 += 64) {
    unsigned int v = (s0 + t < nb) ? bsums[s0 + t] : 0u;
    unsigned int incl = v;
#pragma unroll
    for (int d = 1; d < 64; d <<= 1) {
      unsigned int u = __shfl_up(incl, d, 64);
      if (t >= d) incl += u;
    }
    if (s0 + t < nb) bbase[s0 + t] = run + incl - v;
    run += __shfl(incl, 63, 64);
  }
}

__global__ __launch_bounds__(256) void scan_final_kernel(
    const unsigned int* __restrict__ count,
    const unsigned int* __restrict__ bbase, unsigned int* __restrict__ offsets,
    float* __restrict__ dinv, int n, int E) {
  int base = blockIdx.x * 1024 + threadIdx.x * 4;
  unsigned int c[4];
  if (base + 4 <= n) {
    uint4 cv = *(const uint4*)&count[base];
    c[0] = cv.x; c[1] = cv.y; c[2] = cv.z; c[3] = cv.w;
  } else {
#pragma unroll
    for (int j = 0; j < 4; ++j) c[j] = (base + j < n) ? count[base + j] : 0u;
  }
  unsigned int tsum = c[0] + c[1] + c[2] + c[3];
  unsigned int incl = tsum;
#pragma unroll
  for (int d = 1; d < 64; d <<= 1) {
    unsigned int u = __shfl_up(incl, d, 64);
    if ((threadIdx.x & 63) >= d) incl += u;
  }
  __shared__ unsigned int wsum[4];
  int wave = threadIdx.x >> 6;
  if ((threadIdx.x & 63) == 63) wsum[wave] = incl;
  __syncthreads();
  unsigned int ex = bbase[blockIdx.x] + incl - tsum;
  for (int w = 0; w < wave; ++w) ex += wsum[w];
  unsigned int o[4];
  float dv[4];
#pragma unroll
  for (int j = 0; j < 4; ++j) {
    o[j] = ex;
    ex += c[j];
    dv[j] = rsqrtf((float)(1u + c[j]));
  }
  if (base + 4 <= n) {
    *(uint4*)&offsets[base] = make_uint4(o[0], o[1], o[2], o[3]);
    *(float4*)&dinv[base] = make_float4(dv[0], dv[1], dv[2], dv[3]);
  } else {
#pragma unroll
    for (int j = 0; j < 4; ++j)
      if (base + j < n) {
        offsets[base + j] = o[j];
        dinv[base + j] = dv[j];
      }
  }
  if (blockIdx.x == 0 && threadIdx.x == 0) offsets[n] = (unsigned int)E;
}

// ---------------------------------------------------------------------------
// Fill CSR buckets: for each edge, ebuf[offsets[col] + pos] = row.
// ---------------------------------------------------------------------------
__global__ void fill_kernel(const void* __restrict__ ei, int E,
                            const int* __restrict__ flag,
                            const unsigned int* __restrict__ offsets,
                            unsigned int* __restrict__ cursor,
                            int* __restrict__ ebuf) {
  int is64 = *flag;
  for (int e = blockIdx.x * blockDim.x + threadIdx.x; e < E;
       e += gridDim.x * blockDim.x) {
    int row = edge_val(ei, is64, e);
    int col = edge_val(ei, is64, (long long)E + e);
    unsigned int pos = atomicAdd(&cursor[col], 1u);
    ebuf[offsets[col] + pos] = row;
  }
}

// ---------------------------------------------------------------------------
// GEMM [N,128] @ [128,128]. W in LDS, 32 A-rows staged/iter. Wave: 8 rows x
// cols {2*lane, 2*lane+1}. Optional relu, per-row output scale (dinv), and
// bf16-packed output (for the aggregation gather).
// ---------------------------------------------------------------------------
template <int RELU, int OUT_BF16>
__global__ __launch_bounds__(256, 2) void gemm128_kernel(
    const float* __restrict__ A, const float* __restrict__ W,
    const float* __restrict__ bias, const float* __restrict__ row_scale,
    void* __restrict__ out, int nrows) {
  __shared__ float Wl[HID * HID];
  __shared__ float Zl[32][HID];
  for (int i = threadIdx.x; i < HID * HID; i += 256) Wl[i] = W[i];
  int wave = threadIdx.x >> 6, lane = threadIdx.x & 63;
  float b0 = bias ? bias[2 * lane] : 0.f;
  float b1v = bias ? bias[2 * lane + 1] : 0.f;
  __syncthreads();
  for (int base = blockIdx.x * 32; base < nrows; base += gridDim.x * 32) {
    int nr = min(32, nrows - base);
    const float4* src = (const float4*)(A + (size_t)base * HID);
    for (int i = threadIdx.x; i < nr * 32; i += 256)
      ((float4*)&Zl[0][0])[i] = src[i];
    __syncthreads();
    float2 acc[8];
#pragma unroll
    for (int r = 0; r < 8; ++r) acc[r] = make_float2(0.f, 0.f);
    int r0 = wave * 8;
#pragma unroll 2
    for (int k4 = 0; k4 < 32; ++k4) {
      float4 zq[8];
#pragma unroll
      for (int r = 0; r < 8; ++r) zq[r] = *(const float4*)&Zl[r0 + r][k4 * 4];
#pragma unroll
      for (int kk = 0; kk < 4; ++kk) {
        float2 w = *(const float2*)&Wl[(k4 * 4 + kk) * HID + 2 * lane];
#pragma unroll
        for (int r = 0; r < 8; ++r) {
          float zv = ((const float*)&zq[r])[kk];
          acc[r].x = fmaf(zv, w.x, acc[r].x);
          acc[r].y = fmaf(zv, w.y, acc[r].y);
        }
      }
    }
#pragma unroll
    for (int r = 0; r < 8; ++r) {
      int row = r0 + r;
      if (row < nr) {
        float vx = acc[r].x + b0;
        float vy = acc[r].y + b1v;
        if (RELU) {
          vx = fmaxf(vx, 0.f);
          vy = fmaxf(vy, 0.f);
        }
        if (row_scale) {
          float rs = row_scale[base + row];
          vx *= rs;
          vy *= rs;
        }
        if (OUT_BF16) {
          ((unsigned*)out)[(size_t)(base + row) * 64 + lane] = pack_bf16(vx, vy);
        } else {
          ((float2*)out)[(size_t)(base + row) * 64 + lane] =
              make_float2(vx, vy);
        }
      }
    }
    __syncthreads();
  }
}

// ---------------------------------------------------------------------------
// Final GEMM [N,128] @ [128,64] + b2, sigmoid on column 0.
// ---------------------------------------------------------------------------
__global__ __launch_bounds__(256) void gemm_out_kernel(
    const float* __restrict__ A, const float* __restrict__ W,
    const float* __restrict__ bias, float* __restrict__ out, int nrows) {
  __shared__ float Wl[HID * ODIM];
  __shared__ float Zl[32][HID];
  for (int i = threadIdx.x; i < HID * ODIM; i += 256) Wl[i] = W[i];
  int wave = threadIdx.x >> 6, lane = threadIdx.x & 63;
  float bc = bias[lane];
  __syncthreads();
  for (int base = blockIdx.x * 32; base < nrows; base += gridDim.x * 32) {
    int nr = min(32, nrows - base);
    const float4* src = (const float4*)(A + (size_t)base * HID);
    for (int i = threadIdx.x; i < nr * 32; i += 256)
      ((float4*)&Zl[0][0])[i] = src[i];
    __syncthreads();
    float acc[8];
#pragma unroll
    for (int r = 0; r < 8; ++r) acc[r] = 0.f;
    int r0 = wave * 8;
#pragma unroll 2
    for (int k4 = 0; k4 < 32; ++k4) {
      float4 zq[8];
#pragma unroll
      for (int r = 0; r < 8; ++r) zq[r] = *(const float4*)&Zl[r0 + r][k4 * 4];
#pragma unroll
      for (int kk = 0; kk < 4; ++kk) {
        float w = Wl[(k4 * 4 + kk) * ODIM + lane];
#pragma unroll
        for (int r = 0; r < 8; ++r) {
          float zv = ((const float*)&zq[r])[kk];
          acc[r] = fmaf(zv, w, acc[r]);
        }
      }
    }
#pragma unroll
    for (int r = 0; r < 8; ++r) {
      int row = r0 + r;
      if (row < nr) {
        float v = acc[r] + bc;
        if (lane == 0) v = 1.f / (1.f + __expf(-v));
        out[(size_t)(base + row) * ODIM + lane] = v;
      }
    }
    __syncthreads();
  }
}

// ---------------------------------------------------------------------------
// Aggregation: one wave per node. xwb is bf16-packed, PRE-SCALED by dinv[src].
// acc = xwb[i] + sum_{j in N(i)} xwb[j]; h2 = relu(acc*dinv[i] + bg).
// Edge loop unrolled x4 for memory-level parallelism. No atomics.
// ---------------------------------------------------------------------------
__global__ __launch_bounds__(256) void agg_kernel(
    const unsigned* __restrict__ xwb, const float* __restrict__ dinv,
    const unsigned int* __restrict__ offsets, const int* __restrict__ ebuf,
    const float* __restrict__ bg, float* __restrict__ h2, int n) {
  int lane = threadIdx.x & 63;
  int wid = (blockIdx.x * blockDim.x + threadIdx.x) >> 6;
  int nw = (gridDim.x * blockDim.x) >> 6;
  float2 bgv = ((const float2*)bg)[lane];
  for (int i = wid; i < n; i += nw) {
    float di = dinv[i];
    unsigned int s = offsets[i];
    unsigned int e = offsets[i + 1];
    unsigned uself = xwb[(size_t)i * 64 + lane];
    float ax = bf16_lo(uself), ay = bf16_hi(uself);
    unsigned int t = s;
    for (; t + 4 <= e; t += 4) {
      int r0 = __builtin_amdgcn_readfirstlane(ebuf[t]);
      int r1 = __builtin_amdgcn_readfirstlane(ebuf[t + 1]);
      int r2 = __builtin_amdgcn_readfirstlane(ebuf[t + 2]);
      int r3 = __builtin_amdgcn_readfirstlane(ebuf[t + 3]);
      unsigned u0 = xwb[(size_t)r0 * 64 + lane];
      unsigned u1 = xwb[(size_t)r1 * 64 + lane];
      unsigned u2 = xwb[(size_t)r2 * 64 + lane];
      unsigned u3 = xwb[(size_t)r3 * 64 + lane];
      ax += bf16_lo(u0) + bf16_lo(u1) + bf16_lo(u2) + bf16_lo(u3);
      ay += bf16_hi(u0) + bf16_hi(u1) + bf16_hi(u2) + bf16_hi(u3);
    }
    for (; t < e; ++t) {
      int r = __builtin_amdgcn_readfirstlane(ebuf[t]);
      unsigned u = xwb[(size_t)r * 64 + lane];
      ax += bf16_lo(u);
      ay += bf16_hi(u);
    }
    float2 o;
    o.x = fmaxf(fmaf(ax, di, bgv.x), 0.f);
    o.y = fmaxf(fmaf(ay, di, bgv.y), 0.f);
    ((float2*)h2)[(size_t)i * 64 + lane] = o;
  }
}

// ---------------------------------------------------------------------------
static inline size_t align16(size_t x) { return (x + 15) & ~(size_t)15; }

extern "C" void kernel_launch(void* const* d_in, const int* in_sizes, int n_in,
                              void* d_out, int out_size, void* d_ws,
                              size_t ws_size, hipStream_t stream) {
  const float* z = (const float*)d_in[0];
  const float* W1 = (const float*)d_in[1];
  const float* b1 = (const float*)d_in[2];
  const float* Wg = (const float*)d_in[3];
  const float* bg = (const float*)d_in[4];
  const float* W2 = (const float*)d_in[5];
  const float* b2 = (const float*)d_in[6];
  const void* ei = d_in[7];

  int N = in_sizes[0] / HID;
  int E = in_sizes[7] / 2;
  int NB = (N + 1023) / 1024;

  char* ws = (char*)d_ws;
  size_t szH = align16((size_t)N * HID * sizeof(float));
  size_t szXW = align16((size_t)N * 64 * sizeof(unsigned));
  float* h = (float*)ws;                     // [N,128] f32 (reused for h2)
  unsigned* xwb = (unsigned*)(ws + szH);     // [N,64] packed bf16x2, pre-scaled
  char* p = ws + szH + szXW;
  float* dinv = (float*)p;                   p += align16((size_t)N * 4);
  unsigned int* offsets = (unsigned int*)p;  p += align16((size_t)(N + 1) * 4);
  unsigned int* count = (unsigned int*)p;    p += align16((size_t)N * 4);
  unsigned int* cursor = (unsigned int*)p;   p += align16((size_t)N * 4);
  int* ebuf = (int*)p;                       p += align16((size_t)E * 4);
  int* flag = (int*)p;                       p += align16(4);
  unsigned int* bsums = (unsigned int*)p;    p += align16((size_t)NB * 4);
  unsigned int* bbase = (unsigned int*)p;

  // zero count + cursor (contiguous region)
  hipMemsetAsync(count, 0, (size_t)((char*)ebuf - (char*)count), stream);

  detect_idx_kernel<<<1, 64, 0, stream>>>((const unsigned int*)ei, flag);

  // h = relu(z @ W1 + b1)
  gemm128_kernel<1, 0><<<512, 256, 0, stream>>>(z, W1, b1, nullptr, h, N);

  // CSR build: count -> 3-pass scan -> fill
  count_kernel<<<1024, 256, 0, stream>>>(ei, E, flag, count);
  scan_part_kernel<<<NB, 256, 0, stream>>>(count, bsums, N);
  scan_top_kernel<<<1, 64, 0, stream>>>(bsums, bbase, NB);
  scan_final_kernel<<<NB, 256, 0, stream>>>(count, bbase, offsets, dinv, N, E);
  fill_kernel<<<1024, 256, 0, stream>>>(ei, E, flag, offsets, cursor, ebuf);

  // xwb = bf16( (h @ Wg) * dinv[row] )
  gemm128_kernel<0, 1><<<512, 256, 0, stream>>>(h, Wg, nullptr, dinv, xwb, N);

  // h2 = relu(agg * dinv + bg)   (overwrites h)
  agg_kernel<<<2048, 256, 0, stream>>>(xwb, dinv, offsets, ebuf, bg, h, N);

  // out = h2 @ W2 + b2, sigmoid col 0
  gemm_out_kernel<<<768, 256, 0, stream>>>(h, W2, b2, (float*)d_out, N);
}

// Round 4
// 192.428 us; speedup vs baseline: 1.9591x; 1.2202x over previous
//
#include <hip/hip_runtime.h>
#include <hip/hip_bf16.h>
#include <math.h>

#define HID 128
#define ODIM 64

typedef __bf16 bf16x8 __attribute__((ext_vector_type(8)));
typedef float f32x4 __attribute__((ext_vector_type(4)));

union FragU {
  unsigned u[4];
  bf16x8 v;
};

// ---------------------------------------------------------------------------
// bf16 helpers (RNE)
// ---------------------------------------------------------------------------
__device__ inline unsigned pack_bf16(float a, float b) {
  unsigned ua = __float_as_uint(a), ub = __float_as_uint(b);
  ua += 0x7fffu + ((ua >> 16) & 1u);
  ub += 0x7fffu + ((ub >> 16) & 1u);
  return (ua >> 16) | (ub & 0xffff0000u);
}
__device__ inline float bf16_lo(unsigned u) { return __uint_as_float(u << 16); }
__device__ inline float bf16_hi(unsigned u) {
  return __uint_as_float(u & 0xffff0000u);
}
__device__ inline unsigned short bf16_of(float v) {
  unsigned uv = __float_as_uint(v);
  uv += 0x7fffu + ((uv >> 16) & 1u);
  return (unsigned short)(uv >> 16);
}

// ---------------------------------------------------------------------------
// Detect whether edge_index buffer is int64 (JAX x64 on) or int32.
// ---------------------------------------------------------------------------
__global__ void detect_idx_kernel(const unsigned int* __restrict__ ei_words,
                                  int* __restrict__ flag) {
  int t = threadIdx.x;  // 64 threads
  unsigned int v = ei_words[2 * t + 1];
  unsigned long long b = __ballot(v == 0u);
  if (t == 0) *flag = (b == 0xFFFFFFFFFFFFFFFFull) ? 1 : 0;
}

__device__ inline int edge_val(const void* ei, int is64, long long idx) {
  if (is64) return (int)((const long long*)ei)[idx];
  return ((const int*)ei)[idx];
}

// ---------------------------------------------------------------------------
// In-degree count (targets = col = edge_index[1]).
// ---------------------------------------------------------------------------
__global__ void count_kernel(const void* __restrict__ ei, int E,
                             const int* __restrict__ flag,
                             unsigned int* __restrict__ count) {
  int is64 = *flag;
  for (int e = blockIdx.x * blockDim.x + threadIdx.x; e < E;
       e += gridDim.x * blockDim.x) {
    int col = edge_val(ei, is64, (long long)E + e);
    atomicAdd(&count[col], 1u);
  }
}

// ---------------------------------------------------------------------------
// 3-pass device-wide exclusive scan of count -> offsets, plus dinv.
// ---------------------------------------------------------------------------
__global__ __launch_bounds__(256) void scan_part_kernel(
    const unsigned int* __restrict__ count, unsigned int* __restrict__ bsums,
    int n) {
  int base = blockIdx.x * 1024 + threadIdx.x * 4;
  unsigned int s = 0;
  if (base + 4 <= n) {
    uint4 c = *(const uint4*)&count[base];
    s = c.x + c.y + c.z + c.w;
  } else {
#pragma unroll
    for (int j = 0; j < 4; ++j) s += (base + j < n) ? count[base + j] : 0u;
  }
#pragma unroll
  for (int d = 32; d >= 1; d >>= 1) s += __shfl_down(s, d, 64);
  __shared__ unsigned int red[4];
  int wave = threadIdx.x >> 6, lane = threadIdx.x & 63;
  if (lane == 0) red[wave] = s;
  __syncthreads();
  if (threadIdx.x == 0) bsums[blockIdx.x] = red[0] + red[1] + red[2] + red[3];
}

__global__ void scan_top_kernel(const unsigned int* __restrict__ bsums,
                                unsigned int* __restrict__ bbase, int nb) {
  int t = threadIdx.x;  // 64 threads, single wave
  unsigned int run = 0;
  for (int s0 = 0; s0 < nb; s0 += 64) {
    unsigned int v = (s0 + t < nb) ? bsums[s0 + t] : 0u;
    unsigned int incl = v;
#pragma unroll
    for (int d = 1; d < 64; d <<= 1) {
      unsigned int u = __shfl_up(incl, d, 64);
      if (t >= d) incl += u;
    }
    if (s0 + t < nb) bbase[s0 + t] = run + incl - v;
    run += __shfl(incl, 63, 64);
  }
}

__global__ __launch_bounds__(256) void scan_final_kernel(
    const unsigned int* __restrict__ count,
    const unsigned int* __restrict__ bbase, unsigned int* __restrict__ offsets,
    float* __restrict__ dinv, int n, int E) {
  int base = blockIdx.x * 1024 + threadIdx.x * 4;
  unsigned int c[4];
  if (base + 4 <= n) {
    uint4 cv = *(const uint4*)&count[base];
    c[0] = cv.x; c[1] = cv.y; c[2] = cv.z; c[3] = cv.w;
  } else {
#pragma unroll
    for (int j = 0; j < 4; ++j) c[j] = (base + j < n) ? count[base + j] : 0u;
  }
  unsigned int tsum = c[0] + c[1] + c[2] + c[3];
  unsigned int incl = tsum;
#pragma unroll
  for (int d = 1; d < 64; d <<= 1) {
    unsigned int u = __shfl_up(incl, d, 64);
    if ((threadIdx.x & 63) >= d) incl += u;
  }
  __shared__ unsigned int wsum[4];
  int wave = threadIdx.x >> 6;
  if ((threadIdx.x & 63) == 63) wsum[wave] = incl;
  __syncthreads();
  unsigned int ex = bbase[blockIdx.x] + incl - tsum;
  for (int w = 0; w < wave; ++w) ex += wsum[w];
  unsigned int o[4];
  float dv[4];
#pragma unroll
  for (int j = 0; j < 4; ++j) {
    o[j] = ex;
    ex += c[j];
    dv[j] = rsqrtf((float)(1u + c[j]));
  }
  if (base + 4 <= n) {
    *(uint4*)&offsets[base] = make_uint4(o[0], o[1], o[2], o[3]);
    *(float4*)&dinv[base] = make_float4(dv[0], dv[1], dv[2], dv[3]);
  } else {
#pragma unroll
    for (int j = 0; j < 4; ++j)
      if (base + j < n) {
        offsets[base + j] = o[j];
        dinv[base + j] = dv[j];
      }
  }
  if (blockIdx.x == 0 && threadIdx.x == 0) offsets[n] = (unsigned int)E;
}

// ---------------------------------------------------------------------------
// Fill CSR buckets: for each edge, ebuf[offsets[col] + pos] = row.
// ---------------------------------------------------------------------------
__global__ void fill_kernel(const void* __restrict__ ei, int E,
                            const int* __restrict__ flag,
                            const unsigned int* __restrict__ offsets,
                            unsigned int* __restrict__ cursor,
                            int* __restrict__ ebuf) {
  int is64 = *flag;
  for (int e = blockIdx.x * blockDim.x + threadIdx.x; e < E;
       e += gridDim.x * blockDim.x) {
    int row = edge_val(ei, is64, e);
    int col = edge_val(ei, is64, (long long)E + e);
    unsigned int pos = atomicAdd(&cursor[col], 1u);
    ebuf[offsets[col] + pos] = row;
  }
}

// ---------------------------------------------------------------------------
// Split W (f32, [128][NC] row-major, K-major rows) into bf16 hi/lo fragments
// in MFMA-fragment order: entry e = (tile*4 + s)*64 + lane holds the 8 bf16
// (4 u32) the lane feeds to mfma_f32_16x16x32_bf16 for col-tile `tile`,
// k-step `s`:  k = 32s + (lane>>4)*8 + i,  col = tile*16 + (lane&15).
// ---------------------------------------------------------------------------
__global__ void wfrag_kernel(const float* __restrict__ W,
                             unsigned* __restrict__ Whi,
                             unsigned* __restrict__ Wlo, int NC) {
  int total = (NC / 16) * 4 * 64;
  for (int e = blockIdx.x * blockDim.x + threadIdx.x; e < total;
       e += gridDim.x * blockDim.x) {
    int lane = e & 63;
    int s = (e >> 6) & 3;
    int t = e >> 8;
    int g = lane >> 4, c = lane & 15;
    int col = t * 16 + c;
    unsigned hw[4], lw[4];
#pragma unroll
    for (int j = 0; j < 4; ++j) {
      float a = W[(32 * s + g * 8 + 2 * j) * NC + col];
      float b = W[(32 * s + g * 8 + 2 * j + 1) * NC + col];
      unsigned h = pack_bf16(a, b);
      hw[j] = h;
      lw[j] = pack_bf16(a - bf16_lo(h), b - bf16_hi(h));
    }
    *(uint4*)&Whi[(size_t)e * 4] = make_uint4(hw[0], hw[1], hw[2], hw[3]);
    *(uint4*)&Wlo[(size_t)e * 4] = make_uint4(lw[0], lw[1], lw[2], lw[3]);
  }
}

// ---------------------------------------------------------------------------
// Split-bf16 MFMA GEMM:  out[M,NC] = A[M,128] @ W[128,NC] (+bias, relu,
// row_scale, bf16-out, sigmoid-on-col-0 options).  D = Ah*Wh + Ah*Wl + Al*Wh
// (error ~2^-17, fp32-quality).  Block = 4 waves = 64 rows x 64 cols; A read
// straight from global (no LDS, no barriers); W frags from L2 (frag-ordered).
// ---------------------------------------------------------------------------
template <int NC, int RELU, int OBF16, int SIG0>
__global__ __launch_bounds__(256, 4) void mfma_gemm_kernel(
    const float* __restrict__ A, const unsigned* __restrict__ Whi,
    const unsigned* __restrict__ Wlo, const float* __restrict__ bias,
    const float* __restrict__ row_scale, void* __restrict__ out, int M) {
  int wave = threadIdx.x >> 6, lane = threadIdx.x & 63;
  int g = lane >> 4, c = lane & 15;
  int tiles_m = (M + 63) >> 6;
  int tiles_total = tiles_m * (NC / 64);
  for (int tid = blockIdx.x; tid < tiles_total; tid += gridDim.x) {
    int mt = tid % tiles_m;
    int half = tid / tiles_m;
    int r0 = mt * 64 + wave * 16;
    int rowc = min(r0 + c, M - 1);  // A-frag row = lane&15
    const float* ap = A + (size_t)rowc * 128 + g * 8;
    f32x4 fa[8];
#pragma unroll
    for (int s = 0; s < 4; ++s) {
      fa[2 * s] = *(const f32x4*)(ap + 32 * s);
      fa[2 * s + 1] = *(const f32x4*)(ap + 32 * s + 4);
    }
    f32x4 acc[4];
#pragma unroll
    for (int t = 0; t < 4; ++t) acc[t] = (f32x4){0.f, 0.f, 0.f, 0.f};
#pragma unroll
    for (int s = 0; s < 4; ++s) {
      FragU ah, al;
#pragma unroll
      for (int j = 0; j < 2; ++j) {
        f32x4 p = fa[2 * s + j];
        unsigned h0 = pack_bf16(p[0], p[1]);
        unsigned h1 = pack_bf16(p[2], p[3]);
        ah.u[2 * j] = h0;
        ah.u[2 * j + 1] = h1;
        al.u[2 * j] = pack_bf16(p[0] - bf16_lo(h0), p[1] - bf16_hi(h0));
        al.u[2 * j + 1] = pack_bf16(p[2] - bf16_lo(h1), p[3] - bf16_hi(h1));
      }
#pragma unroll
      for (int tl = 0; tl < 4; ++tl) {
        int e = ((half * 4 + tl) * 4 + s) * 64 + lane;
        FragU wh, wl;
        *(uint4*)wh.u = *(const uint4*)&Whi[(size_t)e * 4];
        *(uint4*)wl.u = *(const uint4*)&Wlo[(size_t)e * 4];
        acc[tl] =
            __builtin_amdgcn_mfma_f32_16x16x32_bf16(ah.v, wh.v, acc[tl], 0, 0, 0);
        acc[tl] =
            __builtin_amdgcn_mfma_f32_16x16x32_bf16(ah.v, wl.v, acc[tl], 0, 0, 0);
        acc[tl] =
            __builtin_amdgcn_mfma_f32_16x16x32_bf16(al.v, wh.v, acc[tl], 0, 0, 0);
      }
    }
    // Epilogue. D row = g*4 + reg, D col = tl*16 + c (verified C/D layout).
    float rs[4];
    if (row_scale) {
#pragma unroll
      for (int r = 0; r < 4; ++r)
        rs[r] = row_scale[min(r0 + g * 4 + r, M - 1)];
    }
#pragma unroll
    for (int tl = 0; tl < 4; ++tl) {
      int colg = half * 64 + tl * 16 + c;
      float bv = bias ? bias[colg] : 0.f;
#pragma unroll
      for (int rg = 0; rg < 4; ++rg) {
        int r = r0 + g * 4 + rg;
        if (r < M) {
          float v = acc[tl][rg] + bv;
          if (RELU) v = fmaxf(v, 0.f);
          if (row_scale) v *= rs[rg];
          if (SIG0 && colg == 0) v = 1.f / (1.f + __expf(-v));
          if (OBF16) {
            ((unsigned short*)out)[(size_t)r * 128 + colg] = bf16_of(v);
          } else {
            ((float*)out)[(size_t)r * NC + colg] = v;
          }
        }
      }
    }
  }
}

// ---------------------------------------------------------------------------
// Aggregation: one wave per node. xwb is bf16 [N][128] (= packed u32 [N][64]),
// PRE-SCALED by dinv[src]. acc = xwb[i] + sum_{j in N(i)} xwb[j];
// h2 = relu(acc*dinv[i] + bg). Edge loop unrolled x4. No atomics.
// ---------------------------------------------------------------------------
__global__ __launch_bounds__(256) void agg_kernel(
    const unsigned* __restrict__ xwb, const float* __restrict__ dinv,
    const unsigned int* __restrict__ offsets, const int* __restrict__ ebuf,
    const float* __restrict__ bg, float* __restrict__ h2, int n) {
  int lane = threadIdx.x & 63;
  int wid = (blockIdx.x * blockDim.x + threadIdx.x) >> 6;
  int nw = (gridDim.x * blockDim.x) >> 6;
  float2 bgv = ((const float2*)bg)[lane];
  for (int i = wid; i < n; i += nw) {
    float di = dinv[i];
    unsigned int s = offsets[i];
    unsigned int e = offsets[i + 1];
    unsigned uself = xwb[(size_t)i * 64 + lane];
    float ax = bf16_lo(uself), ay = bf16_hi(uself);
    unsigned int t = s;
    for (; t + 4 <= e; t += 4) {
      int r0 = __builtin_amdgcn_readfirstlane(ebuf[t]);
      int r1 = __builtin_amdgcn_readfirstlane(ebuf[t + 1]);
      int r2 = __builtin_amdgcn_readfirstlane(ebuf[t + 2]);
      int r3 = __builtin_amdgcn_readfirstlane(ebuf[t + 3]);
      unsigned u0 = xwb[(size_t)r0 * 64 + lane];
      unsigned u1 = xwb[(size_t)r1 * 64 + lane];
      unsigned u2 = xwb[(size_t)r2 * 64 + lane];
      unsigned u3 = xwb[(size_t)r3 * 64 + lane];
      ax += bf16_lo(u0) + bf16_lo(u1) + bf16_lo(u2) + bf16_lo(u3);
      ay += bf16_hi(u0) + bf16_hi(u1) + bf16_hi(u2) + bf16_hi(u3);
    }
    for (; t < e; ++t) {
      int r = __builtin_amdgcn_readfirstlane(ebuf[t]);
      unsigned u = xwb[(size_t)r * 64 + lane];
      ax += bf16_lo(u);
      ay += bf16_hi(u);
    }
    float2 o;
    o.x = fmaxf(fmaf(ax, di, bgv.x), 0.f);
    o.y = fmaxf(fmaf(ay, di, bgv.y), 0.f);
    ((float2*)h2)[(size_t)i * 64 + lane] = o;
  }
}

// ---------------------------------------------------------------------------
static inline size_t align16(size_t x) { return (x + 15) & ~(size_t)15; }

extern "C" void kernel_launch(void* const* d_in, const int* in_sizes, int n_in,
                              void* d_out, int out_size, void* d_ws,
                              size_t ws_size, hipStream_t stream) {
  const float* z = (const float*)d_in[0];
  const float* W1 = (const float*)d_in[1];
  const float* b1 = (const float*)d_in[2];
  const float* Wg = (const float*)d_in[3];
  const float* bg = (const float*)d_in[4];
  const float* W2 = (const float*)d_in[5];
  const float* b2 = (const float*)d_in[6];
  const void* ei = d_in[7];

  int N = in_sizes[0] / HID;
  int E = in_sizes[7] / 2;
  int NB = (N + 1023) / 1024;
  int TM = (N + 63) / 64;

  char* ws = (char*)d_ws;
  size_t szH = align16((size_t)N * HID * sizeof(float));
  size_t szXW = align16((size_t)N * 64 * sizeof(unsigned));
  float* h = (float*)ws;                     // [N,128] f32 (reused for h2)
  unsigned* xwb = (unsigned*)(ws + szH);     // [N,64] u32 = bf16[N,128]
  char* p = ws + szH + szXW;
  float* dinv = (float*)p;                   p += align16((size_t)N * 4);
  unsigned int* offsets = (unsigned int*)p;  p += align16((size_t)(N + 1) * 4);
  unsigned int* count = (unsigned int*)p;    p += align16((size_t)N * 4);
  unsigned int* cursor = (unsigned int*)p;   p += align16((size_t)N * 4);
  int* ebuf = (int*)p;                       p += align16((size_t)E * 4);
  int* flag = (int*)p;                       p += align16(4);
  unsigned int* bsums = (unsigned int*)p;    p += align16((size_t)NB * 4);
  unsigned int* bbase = (unsigned int*)p;    p += align16((size_t)NB * 4);
  unsigned* w1h = (unsigned*)p;              p += 2048 * 16;
  unsigned* w1l = (unsigned*)p;              p += 2048 * 16;
  unsigned* wgh = (unsigned*)p;              p += 2048 * 16;
  unsigned* wgl = (unsigned*)p;              p += 2048 * 16;
  unsigned* w2h = (unsigned*)p;              p += 1024 * 16;
  unsigned* w2l = (unsigned*)p;

  // zero count + cursor (contiguous region)
  hipMemsetAsync(count, 0, (size_t)((char*)ebuf - (char*)count), stream);

  detect_idx_kernel<<<1, 64, 0, stream>>>((const unsigned int*)ei, flag);

  // Weight fragment split (bf16 hi/lo, MFMA fragment order)
  wfrag_kernel<<<8, 256, 0, stream>>>(W1, w1h, w1l, 128);
  wfrag_kernel<<<8, 256, 0, stream>>>(Wg, wgh, wgl, 128);
  wfrag_kernel<<<4, 256, 0, stream>>>(W2, w2h, w2l, 64);

  // h = relu(z @ W1 + b1)
  mfma_gemm_kernel<128, 1, 0, 0>
      <<<2 * TM, 256, 0, stream>>>(z, w1h, w1l, b1, nullptr, h, N);

  // CSR build: count -> 3-pass scan -> fill
  count_kernel<<<1024, 256, 0, stream>>>(ei, E, flag, count);
  scan_part_kernel<<<NB, 256, 0, stream>>>(count, bsums, N);
  scan_top_kernel<<<1, 64, 0, stream>>>(bsums, bbase, NB);
  scan_final_kernel<<<NB, 256, 0, stream>>>(count, bbase, offsets, dinv, N, E);
  fill_kernel<<<1024, 256, 0, stream>>>(ei, E, flag, offsets, cursor, ebuf);

  // xwb = bf16( (h @ Wg) * dinv[row] )
  mfma_gemm_kernel<128, 0, 1, 0>
      <<<2 * TM, 256, 0, stream>>>(h, wgh, wgl, nullptr, dinv, xwb, N);

  // h2 = relu(agg * dinv + bg)   (overwrites h)
  agg_kernel<<<2048, 256, 0, stream>>>(xwb, dinv, offsets, ebuf, bg, h, N);

  // out = h2 @ W2 + b2, sigmoid col 0
  mfma_gemm_kernel<64, 0, 0, 1>
      <<<TM, 256, 0, stream>>>(h, w2h, w2l, b2, nullptr, (float*)d_out, N);
}